// Round 2
// baseline (1569.929 us; speedup 1.0000x reference)
//
#include <hip/hip_runtime.h>
#include <hip/hip_bf16.h>
#include <cstdint>
#include <cstddef>

// CFnetFilter: w_ij = segment_sum(ssp(ssp(dijk@W1+b1)@W2+b2), seg_j)
// ssp(x) = softplus(x) - log(2)
//
// Structure: fully fused, 128 rows/block, 4 waves; each wave owns 32 rows
// end-to-end (GEMM1 -> h in LDS -> GEMM2 -> wijk in LDS -> segmented reduce)
// with NO block barrier. LDS exactly 32 KB -> 5 blocks/CU.

typedef float f32x4 __attribute__((ext_vector_type(4)));
typedef __bf16 bf16x8 __attribute__((ext_vector_type(8)));

static constexpr int   N_TRIPLES = 2000000;
static constexpr int   DIM       = 128;
static constexpr int   NSEG      = 100000;
static constexpr int   ROWS      = 128;     // rows per block (2e6 / 128 = 15625 exact)
static constexpr float LOG2F_    = 0.6931471805599453f;

// softplus only (the -log2 of layer 1 is folded into b2'; layer 2 keeps it)
__device__ __forceinline__ float sp_(float x) {
  float e = __expf(-fabsf(x));
  return fmaxf(x, 0.0f) + __logf(1.0f + e);
}

// Transpose W1,W2 [k][n] f32 -> WT [n][k] bf16 (MFMA B-frags contiguous in k)
__global__ void wt_kernel(const float* __restrict__ W1, const float* __restrict__ W2,
                          __bf16* __restrict__ WT) {
  int t = blockIdx.x * 256 + threadIdx.x;   // 0..16383
  int k = t >> 7;
  int n = t & 127;
  WT[n * 128 + k]         = (__bf16)W1[t];
  WT[16384 + n * 128 + k] = (__bf16)W2[t];
}

// b2'[n] = b2[n] - log2 * sum_k W2[k][n]   (folds layer-1's -log2 into layer-2 bias)
__global__ void bias_kernel(const float* __restrict__ W2, const float* __restrict__ b2,
                            float* __restrict__ b2p) {
  int n = threadIdx.x;
  float s = 0.0f;
  #pragma unroll 8
  for (int k = 0; k < 128; ++k) s += W2[k * 128 + n];
  b2p[n] = b2[n] - LOG2F_ * s;
}

__global__ __launch_bounds__(256, 5) void fused_kernel(
    const float* __restrict__ dijk, const int* __restrict__ seg,
    const __bf16* __restrict__ WT,
    const float* __restrict__ b1v, const float* __restrict__ b2p,
    float* __restrict__ out)
{
  __shared__ __bf16 hbuf[ROWS * DIM];   // exactly 32 KB; h then wijk, swizzled

  const int tid  = threadIdx.x;
  const int lane = tid & 63;
  const int wave = tid >> 6;
  const int l15  = lane & 15;
  const int g    = lane >> 4;           // quarter-wave group (k-group for frags)
  const int r0   = blockIdx.x * ROWS;
  const int wrow = wave * 32;           // this wave's first row within the block

  // biases for this lane's 8 column slots (col = nt*16 + l15)
  float bias1[8], bias2[8];
  #pragma unroll
  for (int nt = 0; nt < 8; ++nt) {
    bias1[nt] = b1v[nt * 16 + l15];
    bias2[nt] = b2p[nt * 16 + l15];
  }

  char* hb = (char*)hbuf;

  // ---------------- GEMM1: h' = softplus(dijk @ W1 + b1) ----------------
  f32x4 acc[2][8] = {};
  {
    const __bf16* WT1 = WT;
    #pragma unroll
    for (int ks = 0; ks < 4; ++ks) {
      bf16x8 afrag[2];
      #pragma unroll
      for (int mt = 0; mt < 2; ++mt) {
        const float* p = dijk + (size_t)(r0 + wrow + mt * 16 + l15) * DIM + ks * 32 + g * 8;
        f32x4 v0 = *(const f32x4*)p;
        f32x4 v1 = *(const f32x4*)(p + 4);
        bf16x8 t8;
        t8[0] = (__bf16)v0[0]; t8[1] = (__bf16)v0[1]; t8[2] = (__bf16)v0[2]; t8[3] = (__bf16)v0[3];
        t8[4] = (__bf16)v1[0]; t8[5] = (__bf16)v1[1]; t8[6] = (__bf16)v1[2]; t8[7] = (__bf16)v1[3];
        afrag[mt] = t8;
      }
      #pragma unroll
      for (int nt = 0; nt < 8; ++nt) {
        bf16x8 bfrag = *(const bf16x8*)(WT1 + (nt * 16 + l15) * DIM + ks * 32 + g * 8);
        acc[0][nt] = __builtin_amdgcn_mfma_f32_16x16x32_bf16(afrag[0], bfrag, acc[0][nt], 0, 0, 0);
        acc[1][nt] = __builtin_amdgcn_mfma_f32_16x16x32_bf16(afrag[1], bfrag, acc[1][nt], 0, 0, 0);
      }
    }
  }

  // bias + softplus, h' -> LDS (bf16, XOR-swizzled). Own-wave rows only.
  #pragma unroll
  for (int mt = 0; mt < 2; ++mt) {
    #pragma unroll
    for (int nt = 0; nt < 8; ++nt) {
      #pragma unroll
      for (int j = 0; j < 4; ++j) {
        int row = wrow + mt * 16 + g * 4 + j;   // C/D: row=(lane>>4)*4+j
        int col = nt * 16 + l15;                //      col=lane&15
        float hv = sp_(acc[mt][nt][j] + bias1[nt]);
        *(__bf16*)(hb + row * 256 + ((col * 2) ^ ((row & 7) << 4))) = (__bf16)hv;
      }
    }
  }

  // ---------------- GEMM2: w = softplus(h' @ W2 + b2') - log2 ----------------
  f32x4 acc2[2][8] = {};
  {
    const __bf16* WT2 = WT + 16384;
    #pragma unroll
    for (int ks = 0; ks < 4; ++ks) {
      bf16x8 afrag[2];
      #pragma unroll
      for (int mt = 0; mt < 2; ++mt) {
        int row = wrow + mt * 16 + l15;         // A: row=lane&15
        int kb  = (ks * 64 + g * 16) ^ ((row & 7) << 4);
        afrag[mt] = *(const bf16x8*)(hb + row * 256 + kb);
      }
      #pragma unroll
      for (int nt = 0; nt < 8; ++nt) {
        bf16x8 bfrag = *(const bf16x8*)(WT2 + (nt * 16 + l15) * DIM + ks * 32 + g * 8);
        acc2[0][nt] = __builtin_amdgcn_mfma_f32_16x16x32_bf16(afrag[0], bfrag, acc2[0][nt], 0, 0, 0);
        acc2[1][nt] = __builtin_amdgcn_mfma_f32_16x16x32_bf16(afrag[1], bfrag, acc2[1][nt], 0, 0, 0);
      }
    }
  }

  // bias + ssp, wijk -> same LDS rows (own-wave; prior reads complete in-order)
  #pragma unroll
  for (int mt = 0; mt < 2; ++mt) {
    #pragma unroll
    for (int nt = 0; nt < 8; ++nt) {
      #pragma unroll
      for (int j = 0; j < 4; ++j) {
        int row = wrow + mt * 16 + g * 4 + j;
        int col = nt * 16 + l15;
        float wv = sp_(acc2[mt][nt][j] + bias2[nt]) - LOG2F_;
        *(__bf16*)(hb + row * 256 + ((col * 2) ^ ((row & 7) << 4))) = (__bf16)wv;
      }
    }
  }

  // ---------------- segmented reduce (seg_j sorted), per-wave, no barrier ----
  // Wave reduces its OWN 32 rows. Lane owns cols {2*lane, 2*lane+1} (one
  // ds_read_b32 per row, 2-way bank aliasing = free). Segment ids are
  // wave-uniform -> scalar loads + SALU compare/branch. Flushes write 512 B
  // of contiguous floats per wave (good coalescing).
  {
    const int colb = lane * 2;
    const int wr0g = __builtin_amdgcn_readfirstlane(r0 + wrow); // force SGPR base
    const int* sp = seg + wr0g;
    float a0 = 0.0f, a1 = 0.0f;
    int cur = sp[0];
    #pragma unroll
    for (int grp = 0; grp < 4; ++grp) {
      uint32_t v[8];
      #pragma unroll
      for (int i = 0; i < 8; ++i) {
        int row = wrow + grp * 8 + i;
        v[i] = *(const uint32_t*)(hb + row * 256 + ((colb * 2) ^ ((row & 7) << 4)));
      }
      #pragma unroll
      for (int i = 0; i < 8; ++i) {
        int s = sp[grp * 8 + i];           // uniform -> s_load
        if (s != cur) {                    // SALU compare, wave-uniform branch
          atomicAdd(out + (size_t)cur * DIM + colb,     a0);
          atomicAdd(out + (size_t)cur * DIM + colb + 1, a1);
          a0 = 0.0f; a1 = 0.0f; cur = s;
        }
        uint32_t w = v[i];
        a0 += __uint_as_float(w << 16);          // bf16 lo -> f32
        a1 += __uint_as_float(w & 0xffff0000u);  // bf16 hi -> f32
      }
    }
    atomicAdd(out + (size_t)cur * DIM + colb,     a0);
    atomicAdd(out + (size_t)cur * DIM + colb + 1, a1);
  }
}

extern "C" void kernel_launch(void* const* d_in, const int* in_sizes, int n_in,
                              void* d_out, int out_size, void* d_ws, size_t ws_size,
                              hipStream_t stream) {
  const float* dijk = (const float*)d_in[0];
  const int*   seg  = (const int*)d_in[1];
  const float* W1   = (const float*)d_in[2];
  const float* b1   = (const float*)d_in[3];
  const float* W2   = (const float*)d_in[4];
  const float* b2   = (const float*)d_in[5];
  float* out = (float*)d_out;

  float*  b2p = (float*)d_ws;                       // 128 f32
  __bf16* WT  = (__bf16*)((char*)d_ws + 1024);      // 2 * 128*128 bf16 = 64 KB

  // empty segments must be exactly 0; harness doesn't re-poison between replays
  hipMemsetAsync(out, 0, (size_t)NSEG * DIM * sizeof(float), stream);

  wt_kernel<<<64, 256, 0, stream>>>(W1, W2, WT);
  bias_kernel<<<1, 128, 0, stream>>>(W2, b2, b2p);

  fused_kernel<<<N_TRIPLES / ROWS, 256, 0, stream>>>(dijk, seg, WT, b1, b2p, out);
}

// Round 3
// 967.715 us; speedup vs baseline: 1.6223x; 1.6223x over previous
//
#include <hip/hip_runtime.h>
#include <hip/hip_bf16.h>
#include <cstdint>
#include <cstddef>

// CFnetFilter: w_ij = segment_sum(ssp(ssp(dijk@W1+b1)@W2+b2), seg_j)
// ssp(x) = softplus(x) - log(2)
//
// Fully fused, 128 rows/block, 4 waves; each wave owns 32 rows end-to-end
// (GEMM1 -> h in LDS -> GEMM2 -> wijk in LDS -> segmented reduce), NO block
// barrier. LDS exactly 32 KB. __launch_bounds__(256,4): 128-reg budget ->
// 64 VGPR + 64 AGPR accumulators fit with ZERO spills (R2's (256,5) forced
// ~2.5 GB of scratch spill traffic -- never again).

typedef float f32x4 __attribute__((ext_vector_type(4)));
typedef __bf16 bf16x8 __attribute__((ext_vector_type(8)));

static constexpr int   N_TRIPLES = 2000000;
static constexpr int   DIM       = 128;
static constexpr int   NSEG      = 100000;
static constexpr int   ROWS      = 128;     // rows per block (2e6 / 128 exact)
static constexpr float LOG2F_    = 0.6931471805599453f;

// softplus only (layer-1's -log2 is folded into b2'; layer 2 subtracts it)
__device__ __forceinline__ float sp_(float x) {
  float e = __expf(-fabsf(x));
  return fmaxf(x, 0.0f) + __logf(1.0f + e);
}

// Transpose W1,W2 [k][n] f32 -> WT [n][k] bf16 (MFMA B-frags contiguous in k)
__global__ void wt_kernel(const float* __restrict__ W1, const float* __restrict__ W2,
                          __bf16* __restrict__ WT) {
  int t = blockIdx.x * 256 + threadIdx.x;   // 0..16383
  int k = t >> 7;
  int n = t & 127;
  WT[n * 128 + k]         = (__bf16)W1[t];
  WT[16384 + n * 128 + k] = (__bf16)W2[t];
}

// b2'[n] = b2[n] - log2 * sum_k W2[k][n]  (folds layer-1's -log2 into bias 2)
__global__ void bias_kernel(const float* __restrict__ W2, const float* __restrict__ b2,
                            float* __restrict__ b2p) {
  int n = threadIdx.x;
  float s = 0.0f;
  #pragma unroll 8
  for (int k = 0; k < 128; ++k) s += W2[k * 128 + n];
  b2p[n] = b2[n] - LOG2F_ * s;
}

__global__ __launch_bounds__(256, 4) void fused_kernel(
    const float* __restrict__ dijk, const int* __restrict__ seg,
    const __bf16* __restrict__ WT,
    const float* __restrict__ b1v, const float* __restrict__ b2p,
    float* __restrict__ out)
{
  __shared__ __bf16 hbuf[ROWS * DIM];   // exactly 32 KB; h then wijk, swizzled

  const int tid  = threadIdx.x;
  const int lane = tid & 63;
  const int wave = tid >> 6;
  const int l15  = lane & 15;
  const int g    = lane >> 4;           // quarter-wave group (k-group for frags)
  const int r0   = blockIdx.x * ROWS;
  const int wrow = wave * 32;           // this wave's first row within the block

  char* hb = (char*)hbuf;

  // ---- stage ALL 16 dijk loads first (one HBM-latency exposure per wave) ----
  f32x4 va[16];
  {
    const float* p0 = dijk + (size_t)(r0 + wrow + l15) * DIM + g * 8;
    const float* p1 = p0 + (size_t)16 * DIM;
    #pragma unroll
    for (int ks = 0; ks < 4; ++ks) {
      va[ks * 2]         = *(const f32x4*)(p0 + ks * 32);
      va[ks * 2 + 1]     = *(const f32x4*)(p0 + ks * 32 + 4);
      va[8 + ks * 2]     = *(const f32x4*)(p1 + ks * 32);
      va[8 + ks * 2 + 1] = *(const f32x4*)(p1 + ks * 32 + 4);
    }
  }
  bf16x8 a1[2][4];   // [mt][ks]
  #pragma unroll
  for (int mt = 0; mt < 2; ++mt) {
    #pragma unroll
    for (int ks = 0; ks < 4; ++ks) {
      f32x4 v0 = va[mt * 8 + ks * 2];
      f32x4 v1 = va[mt * 8 + ks * 2 + 1];
      bf16x8 t8;
      t8[0] = (__bf16)v0[0]; t8[1] = (__bf16)v0[1]; t8[2] = (__bf16)v0[2]; t8[3] = (__bf16)v0[3];
      t8[4] = (__bf16)v1[0]; t8[5] = (__bf16)v1[1]; t8[6] = (__bf16)v1[2]; t8[7] = (__bf16)v1[3];
      a1[mt][ks] = t8;
    }
  }

  // biases for this lane's 8 column slots (col = nt*16 + l15)
  float bias1[8], bias2[8];
  #pragma unroll
  for (int nt = 0; nt < 8; ++nt) {
    bias1[nt] = b1v[nt * 16 + l15];
    bias2[nt] = b2p[nt * 16 + l15];
  }

  // ---------------- GEMM1: h' = softplus(dijk @ W1 + b1) ----------------
  f32x4 acc[2][8] = {};
  {
    const __bf16* WT1 = WT;
    #pragma unroll
    for (int ks = 0; ks < 4; ++ks) {
      #pragma unroll
      for (int nt = 0; nt < 8; ++nt) {
        bf16x8 bfrag = *(const bf16x8*)(WT1 + (nt * 16 + l15) * DIM + ks * 32 + g * 8);
        acc[0][nt] = __builtin_amdgcn_mfma_f32_16x16x32_bf16(a1[0][ks], bfrag, acc[0][nt], 0, 0, 0);
        acc[1][nt] = __builtin_amdgcn_mfma_f32_16x16x32_bf16(a1[1][ks], bfrag, acc[1][nt], 0, 0, 0);
      }
    }
  }

  // bias + softplus, h' -> LDS (bf16, XOR-swizzled). Own-wave rows only.
  #pragma unroll
  for (int mt = 0; mt < 2; ++mt) {
    #pragma unroll
    for (int nt = 0; nt < 8; ++nt) {
      #pragma unroll
      for (int j = 0; j < 4; ++j) {
        int row = wrow + mt * 16 + g * 4 + j;   // C/D: row=(lane>>4)*4+j
        int col = nt * 16 + l15;                //      col=lane&15
        float hv = sp_(acc[mt][nt][j] + bias1[nt]);
        *(__bf16*)(hb + row * 256 + ((col * 2) ^ ((row & 7) << 4))) = (__bf16)hv;
      }
    }
  }

  // ---------------- GEMM2: w = softplus(h' @ W2 + b2') - log2 ----------------
  f32x4 acc2[2][8] = {};
  {
    const __bf16* WT2 = WT + 16384;
    #pragma unroll
    for (int ks = 0; ks < 4; ++ks) {
      bf16x8 afrag[2];
      #pragma unroll
      for (int mt = 0; mt < 2; ++mt) {
        int row = wrow + mt * 16 + l15;         // A: row=lane&15
        int kb  = (ks * 64 + g * 16) ^ ((row & 7) << 4);
        afrag[mt] = *(const bf16x8*)(hb + row * 256 + kb);
      }
      #pragma unroll
      for (int nt = 0; nt < 8; ++nt) {
        bf16x8 bfrag = *(const bf16x8*)(WT2 + (nt * 16 + l15) * DIM + ks * 32 + g * 8);
        acc2[0][nt] = __builtin_amdgcn_mfma_f32_16x16x32_bf16(afrag[0], bfrag, acc2[0][nt], 0, 0, 0);
        acc2[1][nt] = __builtin_amdgcn_mfma_f32_16x16x32_bf16(afrag[1], bfrag, acc2[1][nt], 0, 0, 0);
      }
    }
  }

  // bias + ssp, wijk -> same LDS rows (own-wave; prior reads complete in-order)
  #pragma unroll
  for (int mt = 0; mt < 2; ++mt) {
    #pragma unroll
    for (int nt = 0; nt < 8; ++nt) {
      #pragma unroll
      for (int j = 0; j < 4; ++j) {
        int row = wrow + mt * 16 + g * 4 + j;
        int col = nt * 16 + l15;
        float wv = sp_(acc2[mt][nt][j] + bias2[nt]) - LOG2F_;
        *(__bf16*)(hb + row * 256 + ((col * 2) ^ ((row & 7) << 4))) = (__bf16)wv;
      }
    }
  }

  // ---------------- segmented reduce (seg_j sorted), per-wave, no barrier ----
  // Wave reduces its OWN 32 rows. Lane owns cols {2*lane, 2*lane+1} (one
  // ds_read_b32 per row, 2-way bank aliasing = free). Segment ids are
  // wave-uniform -> scalar loads + SALU compare/branch.
  {
    const int colb = lane * 2;
    const int wr0g = __builtin_amdgcn_readfirstlane(r0 + wrow); // force SGPR base
    const int* sp = seg + wr0g;
    float a0 = 0.0f, a1 = 0.0f;
    int cur = sp[0];
    #pragma unroll
    for (int grp = 0; grp < 4; ++grp) {
      uint32_t v[8];
      #pragma unroll
      for (int i = 0; i < 8; ++i) {
        int row = wrow + grp * 8 + i;
        v[i] = *(const uint32_t*)(hb + row * 256 + ((colb * 2) ^ ((row & 7) << 4)));
      }
      #pragma unroll
      for (int i = 0; i < 8; ++i) {
        int s = sp[grp * 8 + i];           // uniform -> s_load
        if (s != cur) {                    // SALU compare, wave-uniform branch
          atomicAdd(out + (size_t)cur * DIM + colb,     a0);
          atomicAdd(out + (size_t)cur * DIM + colb + 1, a1);
          a0 = 0.0f; a1 = 0.0f; cur = s;
        }
        uint32_t w = v[i];
        a0 += __uint_as_float(w << 16);          // bf16 lo -> f32
        a1 += __uint_as_float(w & 0xffff0000u);  // bf16 hi -> f32
      }
    }
    atomicAdd(out + (size_t)cur * DIM + colb,     a0);
    atomicAdd(out + (size_t)cur * DIM + colb + 1, a1);
  }
}

extern "C" void kernel_launch(void* const* d_in, const int* in_sizes, int n_in,
                              void* d_out, int out_size, void* d_ws, size_t ws_size,
                              hipStream_t stream) {
  const float* dijk = (const float*)d_in[0];
  const int*   seg  = (const int*)d_in[1];
  const float* W1   = (const float*)d_in[2];
  const float* b1   = (const float*)d_in[3];
  const float* W2   = (const float*)d_in[4];
  const float* b2   = (const float*)d_in[5];
  float* out = (float*)d_out;

  float*  b2p = (float*)d_ws;                       // 128 f32
  __bf16* WT  = (__bf16*)((char*)d_ws + 1024);      // 2 * 128*128 bf16 = 64 KB

  // empty segments must be exactly 0; harness doesn't re-poison between replays
  hipMemsetAsync(out, 0, (size_t)NSEG * DIM * sizeof(float), stream);

  wt_kernel<<<64, 256, 0, stream>>>(W1, W2, WT);
  bias_kernel<<<1, 128, 0, stream>>>(W2, b2, b2p);

  fused_kernel<<<N_TRIPLES / ROWS, 256, 0, stream>>>(dijk, seg, WT, b1, b2p, out);
}